// Round 1
// baseline (36.199 us; speedup 1.0000x reference)
//
#include <hip/hip_runtime.h>

#define THRESH_SQ 0.1f
#define TINY 1e-6f

__global__ void __launch_bounds__(256) se3_kernel(const float* __restrict__ in,
                                                  float* __restrict__ out, int n) {
    int i = blockIdx.x * 256 + threadIdx.x;
    if (i >= n) return;

    // row layout: [rho0, rho1, rho2, w0, w1, w2]; oz=w0, oy=w1, ox=w2
    const float2* p = reinterpret_cast<const float2*>(in) + (size_t)i * 3;
    float2 v0 = p[0];
    float2 v1 = p[1];
    float2 v2 = p[2];
    float r0 = v0.x, r1 = v0.y, r2 = v1.x;
    float oz = v1.y, oy = v2.x, ox = v2.y;

    float aa = ox * ox, bb = oy * oy, cc = oz * oz;
    float t2 = aa + bb + cc;
    float theta = sqrtf(t2);
    float s = __sinf(theta);
    float c = __cosf(theta);

    float sdt = (theta > 0.f) ? (s / theta) : 0.f;

    float t4 = t2 * t2;
    float t6 = t4 * t2;
    float t8 = t4 * t4;
    float t3 = t2 * theta;

    // A = (1-cos)/t2 for t2>0.1, 0 for t2<1e-6, Taylor otherwise
    float A_taylor = 0.5f + t4 / 720.f + t8 / 3628800.f - t2 / 24.f - t6 / 40320.f;
    float A = (t2 > THRESH_SQ) ? ((1.f - c) / t2)
                               : ((t2 < TINY) ? 0.f : A_taylor);

    // B = (theta-sin)/t3 for t3>0.1, 0 for t2<1e-6, Taylor otherwise
    float B_taylor = 1.f / 6.f + t4 / 5040.f + t8 / 39916800.f - t2 / 120.f - t6 / 362880.f;
    float B = (t3 > 0.1f) ? ((theta - s) / t3)
                          : ((t2 < TINY) ? 0.f : B_taylor);

    float ab = ox * oy, ac = ox * oz, bc = oy * oz;

    // R = I + sdt*skew + A*skew^2
    float R00 = 1.f - A * (cc + bb);
    float R01 = -sdt * oz + A * ab;
    float R02 =  sdt * oy + A * ac;
    float R10 =  sdt * oz + A * ab;
    float R11 = 1.f - A * (cc + aa);
    float R12 = -sdt * ox + A * bc;
    float R20 = -sdt * oy + A * ac;
    float R21 =  sdt * ox + A * bc;
    float R22 = 1.f - A * (aa + bb);

    // V = I + A*skew + B*skew^2
    float V00 = 1.f - B * (cc + bb);
    float V01 = -A * oz + B * ab;
    float V02 =  A * oy + B * ac;
    float V10 =  A * oz + B * ab;
    float V11 = 1.f - B * (cc + aa);
    float V12 = -A * ox + B * bc;
    float V20 = -A * oy + B * ac;
    float V21 =  A * ox + B * bc;
    float V22 = 1.f - B * (aa + bb);

    float tr0 = V00 * r0 + V01 * r1 + V02 * r2;
    float tr1 = V10 * r0 + V11 * r1 + V12 * r2;
    float tr2 = V20 * r0 + V21 * r1 + V22 * r2;

    float4* o = reinterpret_cast<float4*>(out) + (size_t)i * 3;
    o[0] = make_float4(R00, R01, R02, tr0);
    o[1] = make_float4(R10, R11, R12, tr1);
    o[2] = make_float4(R20, R21, R22, tr2);
}

extern "C" void kernel_launch(void* const* d_in, const int* in_sizes, int n_in,
                              void* d_out, int out_size, void* d_ws, size_t ws_size,
                              hipStream_t stream) {
    const float* vec = (const float*)d_in[0];
    float* out = (float*)d_out;
    int n = in_sizes[0] / 6;
    int blocks = (n + 255) / 256;
    se3_kernel<<<blocks, 256, 0, stream>>>(vec, out, n);
}

// Round 2
// 27.789 us; speedup vs baseline: 1.3026x; 1.3026x over previous
//
#include <hip/hip_runtime.h>

#define THRESH_SQ 0.1f
#define TINY 1e-6f

__global__ void __launch_bounds__(256) se3_kernel(const float* __restrict__ in,
                                                  float* __restrict__ out, int n) {
    __shared__ float lds[256 * 12];
    int tid = threadIdx.x;
    int i = blockIdx.x * 256 + tid;

    if (i < n) {
        // row layout: [rho0, rho1, rho2, w0, w1, w2]; oz=w0, oy=w1, ox=w2
        const float2* p = reinterpret_cast<const float2*>(in) + (size_t)i * 3;
        float2 v0 = p[0];
        float2 v1 = p[1];
        float2 v2 = p[2];
        float r0 = v0.x, r1 = v0.y, r2 = v1.x;
        float oz = v1.y, oy = v2.x, ox = v2.y;

        float aa = ox * ox, bb = oy * oy, cc = oz * oz;
        float t2 = aa + bb + cc;
        float theta = sqrtf(t2);
        float s = __sinf(theta);
        float c = __cosf(theta);

        float sdt = (theta > 0.f) ? (s / theta) : 0.f;

        float t4 = t2 * t2;
        float t6 = t4 * t2;
        float t8 = t4 * t4;
        float t3 = t2 * theta;

        // A = (1-cos)/t2 for t2>0.1, 0 for t2<1e-6, Taylor otherwise
        float A_taylor = 0.5f + t4 / 720.f + t8 / 3628800.f - t2 / 24.f - t6 / 40320.f;
        float A = (t2 > THRESH_SQ) ? ((1.f - c) / t2)
                                   : ((t2 < TINY) ? 0.f : A_taylor);

        // B = (theta-sin)/t3 for t3>0.1, 0 for t2<1e-6, Taylor otherwise
        float B_taylor = 1.f / 6.f + t4 / 5040.f + t8 / 39916800.f - t2 / 120.f - t6 / 362880.f;
        float B = (t3 > 0.1f) ? ((theta - s) / t3)
                              : ((t2 < TINY) ? 0.f : B_taylor);

        float ab = ox * oy, ac = ox * oz, bc = oy * oz;

        float* l = &lds[tid * 12];
        // R = I + sdt*skew + A*skew^2 ; V = I + A*skew + B*skew^2
        float R00 = 1.f - A * (cc + bb);
        float R01 = -sdt * oz + A * ab;
        float R02 =  sdt * oy + A * ac;
        float R10 =  sdt * oz + A * ab;
        float R11 = 1.f - A * (cc + aa);
        float R12 = -sdt * ox + A * bc;
        float R20 = -sdt * oy + A * ac;
        float R21 =  sdt * ox + A * bc;
        float R22 = 1.f - A * (aa + bb);

        float V00 = 1.f - B * (cc + bb);
        float V01 = -A * oz + B * ab;
        float V02 =  A * oy + B * ac;
        float V10 =  A * oz + B * ab;
        float V11 = 1.f - B * (cc + aa);
        float V12 = -A * ox + B * bc;
        float V20 = -A * oy + B * ac;
        float V21 =  A * ox + B * bc;
        float V22 = 1.f - B * (aa + bb);

        float tr0 = V00 * r0 + V01 * r1 + V02 * r2;
        float tr1 = V10 * r0 + V11 * r1 + V12 * r2;
        float tr2 = V20 * r0 + V21 * r1 + V22 * r2;

        reinterpret_cast<float4*>(l)[0] = make_float4(R00, R01, R02, tr0);
        reinterpret_cast<float4*>(l)[1] = make_float4(R10, R11, R12, tr1);
        reinterpret_cast<float4*>(l)[2] = make_float4(R20, R21, R22, tr2);
    }
    __syncthreads();

    // Coalesced block write: 256 rows * 12 floats = 768 float4s, contiguous.
    int rem = n - blockIdx.x * 256;
    float4* ob = reinterpret_cast<float4*>(out) + (size_t)blockIdx.x * 768;
    const float4* lv = reinterpret_cast<const float4*>(lds);
    if (rem >= 256) {
        ob[tid]       = lv[tid];
        ob[tid + 256] = lv[tid + 256];
        ob[tid + 512] = lv[tid + 512];
    } else if (rem > 0) {
        int nf4 = rem * 3;
        for (int j = tid; j < nf4; j += 256) ob[j] = lv[j];
    }
}

extern "C" void kernel_launch(void* const* d_in, const int* in_sizes, int n_in,
                              void* d_out, int out_size, void* d_ws, size_t ws_size,
                              hipStream_t stream) {
    const float* vec = (const float*)d_in[0];
    float* out = (float*)d_out;
    int n = in_sizes[0] / 6;
    int blocks = (n + 255) / 256;
    se3_kernel<<<blocks, 256, 0, stream>>>(vec, out, n);
}